// Round 11
// baseline (258.051 us; speedup 1.0000x reference)
//
#include <hip/hip_runtime.h>
#include <hip/hip_fp16.h>
#include <stdint.h>
#include <stddef.h>

#define FEAT 128
#define BKT_SHIFT 8           // 256 nodes per bucket
#define TILE 4096             // edges per block in bucket passes
#define MAXB 400              // max buckets supported (n <= 102400)
#define CAP 4608              // fixed region size per bucket (mean 4096 + 8 sigma)

typedef _Float16 half8 __attribute__((ext_vector_type(8)));
typedef float f32x4 __attribute__((ext_vector_type(4)));

// ---------------- init: zero bucket cursors / allocCtr + W fp16-transpose ----------------

__global__ __launch_bounds__(256) void k_initB(int* __restrict__ cursorPad, int* __restrict__ allocCtr,
                                               const float* __restrict__ W1, const float* __restrict__ W2,
                                               _Float16* __restrict__ Wt1, _Float16* __restrict__ Wt2) {
  int i = blockIdx.x * 256 + threadIdx.x;
  if (i < MAXB * 16) cursorPad[i] = 0;
  if (i == 0) allocCtr[0] = 0;
  if (i < 32768) {                      // both 128x128 W transposes
    int which = i >> 14, rem = i & 16383;
    int k = rem >> 7, nn = rem & 127;
    (which ? Wt2 : Wt1)[nn * 128 + k] = (_Float16)((which ? W2 : W1)[rem]);
  }
}

// ---------------- pass 1: scatter edges into FIXED bucket regions ----------------
// pairs entry: (src << 8) | (dst & 255)

__global__ __launch_bounds__(256) void k_bscatter(const int* __restrict__ src, const int* __restrict__ dst,
                                                  int* __restrict__ cursorPad, int* __restrict__ pairs,
                                                  int E, int B) {
  __shared__ int h[MAXB];
  __shared__ int cur[MAXB];
  int t0 = blockIdx.x * TILE;
  int end = min(E, t0 + TILE);
  for (int i = threadIdx.x; i < B; i += 256) h[i] = 0;
  __syncthreads();
  if (end - t0 == TILE) {
    int d[16];
#pragma unroll
    for (int k = 0; k < 16; ++k) {
      d[k] = dst[t0 + threadIdx.x + k * 256];
      atomicAdd(&h[d[k] >> BKT_SHIFT], 1);
    }
    __syncthreads();
    for (int i = threadIdx.x; i < B; i += 256)
      cur[i] = h[i] ? atomicAdd(&cursorPad[i * 16], h[i]) : 0;
    __syncthreads();
#pragma unroll
    for (int k = 0; k < 16; ++k) {
      int e = t0 + threadIdx.x + k * 256;
      int b = d[k] >> BKT_SHIFT;
      int pos = atomicAdd(&cur[b], 1);
      if (pos < CAP) pairs[b * CAP + pos] = (src[e] << 8) | (d[k] & 255);
    }
  } else {
    for (int e = t0 + threadIdx.x; e < end; e += 256) atomicAdd(&h[dst[e] >> BKT_SHIFT], 1);
    __syncthreads();
    for (int i = threadIdx.x; i < B; i += 256)
      cur[i] = h[i] ? atomicAdd(&cursorPad[i * 16], h[i]) : 0;
    __syncthreads();
    for (int e = t0 + threadIdx.x; e < end; e += 256) {
      int dd = dst[e];
      int b = dd >> BKT_SHIFT;
      int pos = atomicAdd(&cur[b], 1);
      if (pos < CAP) pairs[b * CAP + pos] = (src[e] << 8) | (dd & 255);
    }
  }
}

// ---------------- pass 2: per-bucket CSR + fused layer-1 t-table conversion ----------------
// After building rowstart/cnt/dis for its 256 nodes, the block converts those nodes'
// x rows to the pre-scaled fp16 t-table (dis is block-local in LDS).

__global__ __launch_bounds__(256) void k_csrc(const int* __restrict__ pairs, const int* __restrict__ cursorPad,
                                              int* __restrict__ cnt, int* __restrict__ rowstart,
                                              float* __restrict__ dis, int* __restrict__ allocCtr,
                                              int* __restrict__ adj,
                                              const float* __restrict__ x, __half* __restrict__ T0, int n) {
  __shared__ int deg[256];
  __shared__ int scan[256];
  __shared__ int curs[256];
  __shared__ float disS[256];
  __shared__ int base;
  int b = blockIdx.x, t = threadIdx.x;
  int nodeBase = b << BKT_SHIFT;
  int e0 = b * CAP;
  int ecnt = min(cursorPad[b * 16], CAP);
  deg[t] = 0;
  __syncthreads();
  for (int i = t; i < ecnt; i += 256) atomicAdd(&deg[pairs[e0 + i] & 255], 1);
  __syncthreads();
  int d = deg[t];
  int padded = (d + 3) & ~3;            // 16B-aligned adj rows for int4 loads
  scan[t] = padded;
  __syncthreads();
  for (int off = 1; off < 256; off <<= 1) {
    int xg = scan[t];
    int y = (t >= off) ? scan[t - off] : 0;
    __syncthreads();
    scan[t] = xg + y;
    __syncthreads();
  }
  int excl = scan[t] - padded;
  if (t == 255) base = atomicAdd(allocCtr, scan[t]);   // one bump per block
  __syncthreads();
  int rs = base + excl;
  int node = nodeBase + t;
  float dv = rsqrtf((float)(d + 1));     // +1: self-loop included in reference degree
  disS[t] = dv;
  if (node < n) {
    rowstart[node] = rs;
    cnt[node] = d;
    dis[node] = dv;
  }
  curs[t] = rs;
  __syncthreads();                        // covers disS for conv phase too
  for (int i = t; i < ecnt; i += 256) {
    int pk = pairs[e0 + i];
    int pos = atomicAdd(&curs[pk & 255], 1);
    adj[pos] = pk >> 8;
  }
  // conv: T0[node] = dis[node] * x[node] (fp16), cooperative over the block's 256 rows
  for (int idx = t; idx < 256 * 32; idx += 256) {
    int r = idx >> 5, c = idx & 31;                 // row, float4-column
    int nd = nodeBase + r;
    if (nd >= n) continue;
    float di = disS[r];
    float4 v = ((const float4*)(x + (size_t)nd * FEAT))[c];
    __half2 h0 = __floats2half2_rn(di * v.x, di * v.y);
    __half2 h1 = __floats2half2_rn(di * v.z, di * v.w);
    *(__half2*)(T0 + (size_t)nd * FEAT + c * 4)     = h0;
    *(__half2*)(T0 + (size_t)nd * FEAT + c * 4 + 2) = h1;
  }
}

// ---------------- fused aggregation + MFMA GEMM + bias + relu ----------------
// Block = 4 waves = 16 nodes. Each wave aggregates 4 nodes (one 256B row per neighbor,
// int4-batched adj), writes fp16 z-rows into XOR-swizzled LDS. Then each wave MFMAs
// 2 col-tiles of the 16x128 output directly from LDS (mfma_f32_16x16x32_f16).
// OUT_HALF: write T_next = dis .* relu(...) fp16; else final fp32 out.
// LDS swizzle (both sides): byte_in_row ^= (row&7)<<4  [G4/T2].

template <bool OUT_HALF>
__global__ __launch_bounds__(256) void k_fused(const __half* __restrict__ t, const _Float16* __restrict__ Wt,
                                               const float* __restrict__ bias, const float* __restrict__ dis,
                                               void* __restrict__ OutV,
                                               const int* __restrict__ adj, const int* __restrict__ rowstart,
                                               const int* __restrict__ cnt, int n) {
  __shared__ __align__(16) char zb[16 * 256];   // 16 rows x 128 fp16, swizzled
  __shared__ float disL[16];
  const int tid = threadIdx.x, w = tid >> 6, lane = tid & 63;
  const int blockBase = blockIdx.x * 16;

  // ---- aggregation phase: wave w owns local rows w*4 .. w*4+3 ----
  for (int r = 0; r < 4; ++r) {
    int local = w * 4 + r;
    int node = blockBase + local;
    float ax = 0.f, ay = 0.f, di = 0.f;
    if (node < n) {
      int rs = rowstart[node];
      int d = cnt[node];
      di = dis[node];
      float2 a = __half22float2(((const __half2*)(t + (size_t)node * FEAT))[lane]);
      ax = a.x; ay = a.y;
      int p = rs, e = rs + d;
#pragma unroll 2
      for (; p + 4 <= e; p += 4) {
        int4 j4 = *(const int4*)(adj + p);   // aligned, wave-uniform
        float2 h0 = __half22float2(((const __half2*)(t + (size_t)j4.x * FEAT))[lane]);
        float2 h1 = __half22float2(((const __half2*)(t + (size_t)j4.y * FEAT))[lane]);
        float2 h2 = __half22float2(((const __half2*)(t + (size_t)j4.z * FEAT))[lane]);
        float2 h3 = __half22float2(((const __half2*)(t + (size_t)j4.w * FEAT))[lane]);
        ax += (h0.x + h1.x) + (h2.x + h3.x);
        ay += (h0.y + h1.y) + (h2.y + h3.y);
      }
      for (; p < e; ++p) {
        int j = adj[p];
        float2 hv = __half22float2(((const __half2*)(t + (size_t)j * FEAT))[lane]);
        ax += hv.x; ay += hv.y;
      }
    }
    if (lane == 0) disL[local] = di;
    int boff = local * 256 + ((lane * 4) ^ ((local & 7) << 4));   // swizzled write
    *(__half2*)(zb + boff) = __floats2half2_rn(di * ax, di * ay); // z row, fp16
  }
  __syncthreads();

  // ---- MFMA phase: wave w computes col-tiles {2w, 2w+1} for all 16 rows ----
  const int lrow = lane & 15, g4 = lane >> 4;
  half8 af[4];
#pragma unroll
  for (int kk = 0; kk < 4; ++kk) {
    int cb = (kk * 64 + g4 * 16) ^ ((lrow & 7) << 4);             // swizzled read
    af[kk] = *(const half8*)(zb + lrow * 256 + cb);
  }
#pragma unroll
  for (int c2 = 0; c2 < 2; ++c2) {
    const int c = w * 2 + c2;
    f32x4 acc = (f32x4){0.f, 0.f, 0.f, 0.f};
#pragma unroll
    for (int kk = 0; kk < 4; ++kk) {
      half8 bf = *(const half8*)(Wt + (size_t)(c * 16 + lrow) * 128 + kk * 32 + g4 * 8);
      acc = __builtin_amdgcn_mfma_f32_16x16x32_f16(af[kk], bf, acc, 0, 0, 0);
    }
    float bb = bias[c * 16 + lrow];
    const int r0 = g4 * 4;
#pragma unroll
    for (int r = 0; r < 4; ++r) {
      int row = blockBase + r0 + r;
      if (row < n) {
        float vv = fmaxf(acc[r] + bb, 0.f);
        if (OUT_HALF) ((__half*)OutV)[(size_t)row * FEAT + c * 16 + lrow] = __float2half_rn(disL[r0 + r] * vv);
        else          ((float*)OutV)[(size_t)row * FEAT + c * 16 + lrow] = vv;
      }
    }
  }
}

// ---------------- launch ----------------

extern "C" void kernel_launch(void* const* d_in, const int* in_sizes, int n_in,
                              void* d_out, int out_size, void* d_ws, size_t ws_size,
                              hipStream_t stream) {
  const float* x  = (const float*)d_in[0];
  const int*   ei = (const int*)d_in[1];
  const float* W1 = (const float*)d_in[2];
  const float* b1 = (const float*)d_in[3];
  const float* W2 = (const float*)d_in[4];
  const float* b2 = (const float*)d_in[5];
  float* out = (float*)d_out;

  const int n = in_sizes[0] / FEAT;   // 100000
  const int E = in_sizes[1] / 2;      // 1600000
  const int B = (n + 255) >> BKT_SHIFT;   // 391 buckets (<= MAXB)
  const int* srcv = ei;
  const int* dstv = ei + E;

  uintptr_t p = (uintptr_t)d_ws;
  auto balloc = [&](size_t bytes) -> void* {
    void* r = (void*)p;
    p += (bytes + 255) & ~(size_t)255;
    return r;
  };
  __half*    T0   = (__half*)   balloc((size_t)n * FEAT * sizeof(__half)); // layer-1 t-table (dis.*x)
  __half*    T1   = (__half*)   balloc((size_t)n * FEAT * sizeof(__half)); // layer-2 t-table (dis.*h1)
  _Float16*  Wt1  = (_Float16*) balloc(128 * 128 * sizeof(_Float16));
  _Float16*  Wt2  = (_Float16*) balloc(128 * 128 * sizeof(_Float16));
  int*   cnt      = (int*)  balloc((size_t)n * sizeof(int));
  int*   rowstart = (int*)  balloc((size_t)n * sizeof(int));
  float* dis      = (float*)balloc((size_t)n * sizeof(float));
  int*   allocCtr = (int*)  balloc(256);
  int*   cursorPad= (int*)  balloc((size_t)MAXB * 16 * sizeof(int));       // 64B-padded bucket cursors
  int*   pairs    = (int*)  balloc((size_t)MAXB * CAP * sizeof(int));      // fixed bucket regions (packed)
  int*   adj      = (int*)  balloc(((size_t)E + 4 * (size_t)n) * sizeof(int)); // +pad for row alignment
  (void)ws_size; (void)n_in; (void)out_size;

  const int nb  = (n + 255) / 256;
  const int tb  = (E + TILE - 1) / TILE;          // 391 edge tiles
  const int fb  = (n + 15) / 16;                  // fused: 16 nodes per block

  // graph build + layer-1 t-table
  k_initB   <<<nb, 256, 0, stream>>>(cursorPad, allocCtr, W1, W2, Wt1, Wt2);
  k_bscatter<<<tb, 256, 0, stream>>>(srcv, dstv, cursorPad, pairs, E, B);
  k_csrc    <<<B, 256, 0, stream>>>(pairs, cursorPad, cnt, rowstart, dis, allocCtr, adj, x, T0, n);

  // layer 1 fused: T1 = dis .* relu((Â x) W1 + b1)
  k_fused<true> <<<fb, 256, 0, stream>>>(T0, Wt1, b1, dis, T1, adj, rowstart, cnt, n);
  // layer 2 fused: out = relu((Â h1) W2 + b2)   (pooling is identity)
  k_fused<false><<<fb, 256, 0, stream>>>(T1, Wt2, b2, dis, out, adj, rowstart, cnt, n);
}

// Round 13
// 223.526 us; speedup vs baseline: 1.1545x; 1.1545x over previous
//
#include <hip/hip_runtime.h>
#include <hip/hip_fp16.h>
#include <stdint.h>
#include <stddef.h>

#define FEAT 128
#define BKT_SHIFT 8           // 256 nodes per bucket
#define TILE 4096             // edges per block in bucket passes
#define MAXB 400              // max buckets supported (n <= 102400)
#define CAP 4608              // fixed region size per bucket (mean 4096 + 8 sigma)

typedef _Float16 half8 __attribute__((ext_vector_type(8)));
typedef float f32x4 __attribute__((ext_vector_type(4)));

// ---------------- init: zero bucket cursors / allocCtr + W fp16-transpose ----------------

__global__ __launch_bounds__(256) void k_initB(int* __restrict__ cursorPad, int* __restrict__ allocCtr,
                                               const float* __restrict__ W1, const float* __restrict__ W2,
                                               _Float16* __restrict__ Wt1, _Float16* __restrict__ Wt2) {
  int i = blockIdx.x * 256 + threadIdx.x;
  if (i < MAXB * 16) cursorPad[i] = 0;
  if (i == 0) allocCtr[0] = 0;
  if (i < 32768) {                      // both 128x128 W transposes
    int which = i >> 14, rem = i & 16383;
    int k = rem >> 7, nn = rem & 127;
    (which ? Wt2 : Wt1)[nn * 128 + k] = (_Float16)((which ? W2 : W1)[rem]);
  }
}

// ---------------- pass 1: scatter edges into FIXED bucket regions ----------------
// pairs entry: (src << 8) | (dst & 255)

__global__ __launch_bounds__(256) void k_bscatter(const int* __restrict__ src, const int* __restrict__ dst,
                                                  int* __restrict__ cursorPad, int* __restrict__ pairs,
                                                  int E, int B) {
  __shared__ int h[MAXB];
  __shared__ int cur[MAXB];
  int t0 = blockIdx.x * TILE;
  int end = min(E, t0 + TILE);
  for (int i = threadIdx.x; i < B; i += 256) h[i] = 0;
  __syncthreads();
  if (end - t0 == TILE) {
    int d[16];
#pragma unroll
    for (int k = 0; k < 16; ++k) {
      d[k] = dst[t0 + threadIdx.x + k * 256];
      atomicAdd(&h[d[k] >> BKT_SHIFT], 1);
    }
    __syncthreads();
    for (int i = threadIdx.x; i < B; i += 256)
      cur[i] = h[i] ? atomicAdd(&cursorPad[i * 16], h[i]) : 0;
    __syncthreads();
#pragma unroll
    for (int k = 0; k < 16; ++k) {
      int e = t0 + threadIdx.x + k * 256;
      int b = d[k] >> BKT_SHIFT;
      int pos = atomicAdd(&cur[b], 1);
      if (pos < CAP) pairs[b * CAP + pos] = (src[e] << 8) | (d[k] & 255);
    }
  } else {
    for (int e = t0 + threadIdx.x; e < end; e += 256) atomicAdd(&h[dst[e] >> BKT_SHIFT], 1);
    __syncthreads();
    for (int i = threadIdx.x; i < B; i += 256)
      cur[i] = h[i] ? atomicAdd(&cursorPad[i * 16], h[i]) : 0;
    __syncthreads();
    for (int e = t0 + threadIdx.x; e < end; e += 256) {
      int dd = dst[e];
      int b = dd >> BKT_SHIFT;
      int pos = atomicAdd(&cur[b], 1);
      if (pos < CAP) pairs[b * CAP + pos] = (src[e] << 8) | (dd & 255);
    }
  }
}

// ---------------- pass 2: per-bucket CSR (degrees, rowstart, dis, adj placement) ----------------

__global__ __launch_bounds__(256) void k_csr(const int* __restrict__ pairs, const int* __restrict__ cursorPad,
                                             int* __restrict__ cnt, int* __restrict__ rowstart,
                                             float* __restrict__ dis, int* __restrict__ allocCtr,
                                             int* __restrict__ adj, int n) {
  __shared__ int deg[256];
  __shared__ int scan[256];
  __shared__ int curs[256];
  __shared__ int base;
  int b = blockIdx.x, t = threadIdx.x;
  int nodeBase = b << BKT_SHIFT;
  int e0 = b * CAP;
  int ecnt = min(cursorPad[b * 16], CAP);
  deg[t] = 0;
  __syncthreads();
  for (int i = t; i < ecnt; i += 256) atomicAdd(&deg[pairs[e0 + i] & 255], 1);
  __syncthreads();
  int d = deg[t];
  int padded = (d + 3) & ~3;            // 16B-aligned adj rows for k_agg int4 loads
  scan[t] = padded;
  __syncthreads();
  for (int off = 1; off < 256; off <<= 1) {
    int x = scan[t];
    int y = (t >= off) ? scan[t - off] : 0;
    __syncthreads();
    scan[t] = x + y;
    __syncthreads();
  }
  int excl = scan[t] - padded;
  if (t == 255) base = atomicAdd(allocCtr, scan[t]);   // one bump per block
  __syncthreads();
  int rs = base + excl;
  int node = nodeBase + t;
  if (node < n) {
    rowstart[node] = rs;
    cnt[node] = d;
    dis[node] = rsqrtf((float)(d + 1));  // +1: self-loop included in reference degree
  }
  curs[t] = rs;
  __syncthreads();
  for (int i = t; i < ecnt; i += 256) {
    int pk = pairs[e0 + i];
    int pos = atomicAdd(&curs[pk & 255], 1);           // LDS cursor; writes hit block's own region
    adj[pos] = pk >> 8;
  }
}

// ---------------- MFMA GEMM: T = dis .* (A @ W), fp16 out (pre-scaled gather table) ----------------
// A32: A is fp32 (layer-1 input x, converted in-register); else fp16 (h1).
// A-frag: lane: row = lane&15, k = kk*32 + (lane>>4)*8 + i.
// C/D:   lane: col = lane&15, row = (lane>>4)*4 + reg  [m89-verified].

template <bool A32>
__global__ __launch_bounds__(256, 2) void k_gemm(const void* __restrict__ Av,
                                                 const _Float16* __restrict__ Wt,
                                                 const float* __restrict__ dis,
                                                 __half* __restrict__ T, int n, int nwaves) {
  const int wid = (blockIdx.x * 256 + threadIdx.x) >> 6;
  const int lane = threadIdx.x & 63;
  const int lrow = lane & 15;
  const int lk8 = (lane >> 4) * 8;
  const int ngroups = (n + 15) >> 4;

  half8 bf[8][4];
#pragma unroll
  for (int c = 0; c < 8; ++c)
#pragma unroll
    for (int kk = 0; kk < 4; ++kk)
      bf[c][kk] = *(const half8*)(Wt + (size_t)(c * 16 + lrow) * 128 + kk * 32 + lk8);

  for (int g = wid; g < ngroups; g += nwaves) {
    int ar = g * 16 + lrow; if (ar >= n) ar = n - 1;
    half8 af[4];
    if (A32) {
      const float* arow = (const float*)Av + (size_t)ar * 128 + lk8;
#pragma unroll
      for (int kk = 0; kk < 4; ++kk) {
        float4 v0 = *(const float4*)(arow + kk * 32);
        float4 v1 = *(const float4*)(arow + kk * 32 + 4);
        af[kk] = (half8){(_Float16)v0.x, (_Float16)v0.y, (_Float16)v0.z, (_Float16)v0.w,
                         (_Float16)v1.x, (_Float16)v1.y, (_Float16)v1.z, (_Float16)v1.w};
      }
    } else {
      const _Float16* arow = (const _Float16*)Av + (size_t)ar * 128 + lk8;
#pragma unroll
      for (int kk = 0; kk < 4; ++kk) af[kk] = *(const half8*)(arow + kk * 32);
    }
    f32x4 acc[8];
#pragma unroll
    for (int c = 0; c < 8; ++c) acc[c] = (f32x4){0.f, 0.f, 0.f, 0.f};
#pragma unroll
    for (int kk = 0; kk < 4; ++kk)
#pragma unroll
      for (int c = 0; c < 8; ++c)
        acc[c] = __builtin_amdgcn_mfma_f32_16x16x32_f16(af[kk], bf[c][kk], acc[c], 0, 0, 0);
    const int r0 = g * 16 + (lane >> 4) * 4;
#pragma unroll
    for (int r = 0; r < 4; ++r) {
      int row = r0 + r;
      if (row < n) {
        float sc = dis[row];
#pragma unroll
        for (int c = 0; c < 8; ++c)
          T[(size_t)row * 128 + c * 16 + lrow] = __float2half_rn(sc * acc[c][r]);
      }
    }
  }
}

// ---------------- aggregation + bias + relu: val[i] = relu(dis[i]*(t[i] + sum_j t[j]) + b) ----------------
// t pre-scaled by dis (gemm epilogue). FINAL: write fp32 out; else fp16 h (layer-2 GEMM input).

template <bool FINAL>
__global__ __launch_bounds__(256) void k_agg(const __half* __restrict__ t, const float* __restrict__ bias,
                                             const int* __restrict__ adj, const int* __restrict__ rowstart,
                                             const int* __restrict__ cnt, const float* __restrict__ dis,
                                             void* __restrict__ outV, int n) {
  int node = blockIdx.x * 4 + (threadIdx.x >> 6);
  if (node >= n) return;
  int lane = threadIdx.x & 63;
  int rs = rowstart[node];
  int d = cnt[node];
  float di = dis[node];
  float2 bb = ((const float2*)bias)[lane];
  float2 a = __half22float2(((const __half2*)(t + (size_t)node * FEAT))[lane]);
  float ax = a.x, ay = a.y;
  int p = rs, e = rs + d;
#pragma unroll 2
  for (; p + 4 <= e; p += 4) {
    int4 j4 = *(const int4*)(adj + p);   // aligned (rows 16B-aligned), wave-uniform
    float2 h0 = __half22float2(((const __half2*)(t + (size_t)j4.x * FEAT))[lane]);
    float2 h1 = __half22float2(((const __half2*)(t + (size_t)j4.y * FEAT))[lane]);
    float2 h2 = __half22float2(((const __half2*)(t + (size_t)j4.z * FEAT))[lane]);
    float2 h3 = __half22float2(((const __half2*)(t + (size_t)j4.w * FEAT))[lane]);
    ax += (h0.x + h1.x) + (h2.x + h3.x);
    ay += (h0.y + h1.y) + (h2.y + h3.y);
  }
  for (; p < e; ++p) {
    int j = adj[p];
    float2 hv = __half22float2(((const __half2*)(t + (size_t)j * FEAT))[lane]);
    ax += hv.x; ay += hv.y;
  }
  float vx = fmaxf(fmaf(di, ax, bb.x), 0.f);
  float vy = fmaxf(fmaf(di, ay, bb.y), 0.f);
  if (FINAL) ((float2*)((float*)outV + (size_t)node * FEAT))[lane] = make_float2(vx, vy);
  else       ((__half2*)((__half*)outV + (size_t)node * FEAT))[lane] = __floats2half2_rn(vx, vy);
}

// ---------------- launch ----------------

extern "C" void kernel_launch(void* const* d_in, const int* in_sizes, int n_in,
                              void* d_out, int out_size, void* d_ws, size_t ws_size,
                              hipStream_t stream) {
  const float* x  = (const float*)d_in[0];
  const int*   ei = (const int*)d_in[1];
  const float* W1 = (const float*)d_in[2];
  const float* b1 = (const float*)d_in[3];
  const float* W2 = (const float*)d_in[4];
  const float* b2 = (const float*)d_in[5];
  float* out = (float*)d_out;

  const int n = in_sizes[0] / FEAT;   // 100000
  const int E = in_sizes[1] / 2;      // 1600000
  const int B = (n + 255) >> BKT_SHIFT;   // 391 buckets (<= MAXB)
  const int* srcv = ei;
  const int* dstv = ei + E;

  uintptr_t p = (uintptr_t)d_ws;
  auto balloc = [&](size_t bytes) -> void* {
    void* r = (void*)p;
    p += (bytes + 255) & ~(size_t)255;
    return r;
  };
  __half*    T1   = (__half*)   balloc((size_t)n * FEAT * sizeof(__half)); // layer-1 table: dis.*(x@W1)
  __half*    H1   = (__half*)   balloc((size_t)n * FEAT * sizeof(__half)); // h1 = relu(agg + b1)
  __half*    T2   = (__half*)   balloc((size_t)n * FEAT * sizeof(__half)); // layer-2 table: dis.*(h1@W2)
  _Float16*  Wt1  = (_Float16*) balloc(128 * 128 * sizeof(_Float16));
  _Float16*  Wt2  = (_Float16*) balloc(128 * 128 * sizeof(_Float16));
  int*   cnt      = (int*)  balloc((size_t)n * sizeof(int));
  int*   rowstart = (int*)  balloc((size_t)n * sizeof(int));
  float* dis      = (float*)balloc((size_t)n * sizeof(float));
  int*   allocCtr = (int*)  balloc(256);
  int*   cursorPad= (int*)  balloc((size_t)MAXB * 16 * sizeof(int));       // 64B-padded bucket cursors
  int*   pairs    = (int*)  balloc((size_t)MAXB * CAP * sizeof(int));      // fixed bucket regions (packed)
  int*   adj      = (int*)  balloc(((size_t)E + 4 * (size_t)n) * sizeof(int)); // +pad for row alignment
  (void)ws_size; (void)n_in; (void)out_size;

  const int nb  = (n + 255) / 256;
  const int tb  = (E + TILE - 1) / TILE;          // 391 edge tiles
  const int ab  = (n + 3) / 4;                    // agg: 4 nodes (waves) per block
  const int gemmBlocks = 512;                     // 2048 waves, grid-stride over 6250 row-groups
  const int nwaves = gemmBlocks * 4;

  // graph build (fixed-region bucket scatter + per-bucket CSR)
  k_initB   <<<nb, 256, 0, stream>>>(cursorPad, allocCtr, W1, W2, Wt1, Wt2);
  k_bscatter<<<tb, 256, 0, stream>>>(srcv, dstv, cursorPad, pairs, E, B);
  k_csr     <<<B, 256, 0, stream>>>(pairs, cursorPad, cnt, rowstart, dis, allocCtr, adj, n);

  // layer 1: T1 = dis.*(x@W1)  ->  H1 = relu(di*agg(T1) + b1)
  k_gemm<true>  <<<gemmBlocks, 256, 0, stream>>>(x, Wt1, dis, T1, n, nwaves);
  k_agg<false>  <<<ab, 256, 0, stream>>>(T1, b1, adj, rowstart, cnt, dis, H1, n);

  // layer 2: T2 = dis.*(H1@W2) ->  out = relu(di*agg(T2) + b2)  (pooling is identity)
  k_gemm<false> <<<gemmBlocks, 256, 0, stream>>>(H1, Wt2, dis, T2, n, nwaves);
  k_agg<true>   <<<ab, 256, 0, stream>>>(T2, b2, adj, rowstart, cnt, dis, out, n);
}